// Round 2
// baseline (19267.294 us; speedup 1.0000x reference)
//
#include <hip/hip_runtime.h>
#include <cstdint>

#define NN 300000
#define NE 600000
#define HD 128
#define NL 5
#define NG 8192
#define AVOC 128
#define BVOC 8
#define NAF 9
#define NBF 3
#define BN_EPS 1e-5f

typedef unsigned short u16;
typedef unsigned int u32;

// Workspace budget note: round-0 version needed ~313 MB and the small accumulators
// sat past the 307 MB mark -> suspected d_ws overflow -> GPU memory fault.
// This version: small buffers first, bf16 node storage. Total ~225 MB:
//   stats 20KB | pooled 4MB | inv 1.2MB | B fp32 153.6MB | A bf16 76.8MB

static __device__ __forceinline__ void atomAddF(float* p, float v) { unsafeAtomicAdd(p, v); }

static __device__ __forceinline__ float bf2f(u16 v) {
  union { u32 u; float f; } c; c.u = ((u32)v) << 16; return c.f;
}
static __device__ __forceinline__ u16 f2bf(float f) {
  union { float f; u32 u; } c; c.f = f;
  u32 u = c.u;
  return (u16)((u + 0x7FFFu + ((u >> 16) & 1u)) >> 16);  // RNE
}
static __device__ __forceinline__ void unp8(uint4 p, float* v) {
  v[0] = bf2f((u16)(p.x & 0xffff)); v[1] = bf2f((u16)(p.x >> 16));
  v[2] = bf2f((u16)(p.y & 0xffff)); v[3] = bf2f((u16)(p.y >> 16));
  v[4] = bf2f((u16)(p.z & 0xffff)); v[5] = bf2f((u16)(p.z >> 16));
  v[6] = bf2f((u16)(p.w & 0xffff)); v[7] = bf2f((u16)(p.w >> 16));
}
static __device__ __forceinline__ uint4 pk8(const float* v) {
  uint4 p;
  p.x = ((u32)f2bf(v[1]) << 16) | f2bf(v[0]);
  p.y = ((u32)f2bf(v[3]) << 16) | f2bf(v[2]);
  p.z = ((u32)f2bf(v[5]) << 16) | f2bf(v[4]);
  p.w = ((u32)f2bf(v[7]) << 16) | f2bf(v[6]);
  return p;
}

// ---------------- atom encoder: A[n,c] (bf16) = sum_f atom_emb[f, x[n,f], c] ----------------
__global__ __launch_bounds__(256) void atom_encoder_k(const int* __restrict__ x,
    const float* __restrict__ emb, u16* __restrict__ A) {
  int gid = blockIdx.x * 256 + threadIdx.x;
  if (gid >= NN * 16) return;
  int n = gid >> 4, c8 = gid & 15;
  float acc[8] = {0.f, 0.f, 0.f, 0.f, 0.f, 0.f, 0.f, 0.f};
#pragma unroll
  for (int f = 0; f < NAF; f++) {
    int v = x[n * NAF + f];
    const float* e = emb + ((size_t)(f * AVOC + v)) * HD + c8 * 8;
    float4 e0 = *(const float4*)e;
    float4 e1 = *(const float4*)(e + 4);
    acc[0] += e0.x; acc[1] += e0.y; acc[2] += e0.z; acc[3] += e0.w;
    acc[4] += e1.x; acc[5] += e1.y; acc[6] += e1.z; acc[7] += e1.w;
  }
  *(uint4*)(A + (size_t)n * HD + c8 * 8) = pk8(acc);
}

// ---------------- degree + inverse ----------------
__global__ __launch_bounds__(256) void deg_k(const int* __restrict__ ei, float* __restrict__ deg) {
  int e = blockIdx.x * 256 + threadIdx.x;
  if (e < NE) atomAddF(&deg[ei[e]], 1.0f);
}

__global__ __launch_bounds__(256) void inv_k(float* __restrict__ deg) {
  int n = blockIdx.x * 256 + threadIdx.x;
  if (n < NN) deg[n] = 1.0f / (deg[n] + 1.0f);
}

// ---------------- bond embedding scatter-add into B[row] (fp32) ----------------
__global__ __launch_bounds__(256) void bond_k(const int* __restrict__ ei, const int* __restrict__ ea,
    const float* __restrict__ be, float* __restrict__ B) {
  int gid = blockIdx.x * 256 + threadIdx.x;
  if (gid >= NE * 32) return;
  int e = gid >> 5, c4 = gid & 31;
  int r = ei[e];
  int a0 = ea[e * 3 + 0], a1 = ea[e * 3 + 1], a2 = ea[e * 3 + 2];
  float4 v0 = ((const float4*)(be + (size_t)a0 * HD))[c4];
  float4 v1 = ((const float4*)(be + (size_t)(BVOC + a1) * HD))[c4];
  float4 v2 = ((const float4*)(be + (size_t)(2 * BVOC + a2) * HD))[c4];
  float* dst = B + (size_t)r * HD + c4 * 4;
  atomAddF(dst + 0, v0.x + v1.x + v2.x);
  atomAddF(dst + 1, v0.y + v1.y + v2.y);
  atomAddF(dst + 2, v0.z + v1.z + v2.z);
  atomAddF(dst + 3, v0.w + v1.w + v2.w);
}

// ---------------- h_in = h + B*inv -> A (bf16); B = (1+eps)*h_in (fp32) ----------------
__global__ __launch_bounds__(256) void hinz_k(u16* __restrict__ A, float* __restrict__ B,
    const float* __restrict__ inv, const float* __restrict__ eps, int l) {
  int gid = blockIdx.x * 256 + threadIdx.x;
  if (gid >= NN * 16) return;
  int n = gid >> 4, c8 = gid & 15;
  float iv = inv[n];
  float s = 1.0f + eps[l];
  uint4 pa = *(const uint4*)(A + (size_t)n * HD + c8 * 8);
  float a[8]; unp8(pa, a);
  float* bp = B + (size_t)n * HD + c8 * 8;
  float4 b0 = *(const float4*)bp;
  float4 b1 = *(const float4*)(bp + 4);
  float bv[8] = {b0.x, b0.y, b0.z, b0.w, b1.x, b1.y, b1.z, b1.w};
  float h[8];
#pragma unroll
  for (int j = 0; j < 8; j++) h[j] = fmaf(bv[j], iv, a[j]);
  *(uint4*)(A + (size_t)n * HD + c8 * 8) = pk8(h);
  *(float4*)bp = make_float4(s * h[0], s * h[1], s * h[2], s * h[3]);
  *(float4*)(bp + 4) = make_float4(s * h[4], s * h[5], s * h[6], s * h[7]);
}

// ---------------- aggr: B[col] += A[row]  (z accumulates directly) ----------------
__global__ __launch_bounds__(256) void aggr_k(const int* __restrict__ ei,
    const u16* __restrict__ A, float* __restrict__ B) {
  int gid = blockIdx.x * 256 + threadIdx.x;
  if (gid >= NE * 16) return;
  int e = gid >> 4, c8 = gid & 15;
  int r = ei[e];
  int c = ei[NE + e];
  uint4 p = *(const uint4*)(A + (size_t)r * HD + c8 * 8);
  float v[8]; unp8(p, v);
  float* dst = B + (size_t)c * HD + c8 * 8;
#pragma unroll
  for (int j = 0; j < 8; j++) atomAddF(dst + j, v[j]);
}

// ---------------- GEMM: C[N,128] = f(A)[N,128] @ W[128,128] + bias, + BN stats ----------------
// IN_BF16: A is bf16; OUT_BF16: C written bf16; FUSE: apply relu(A*scale+shift) while staging.
template<bool IN_BF16, bool OUT_BF16, bool FUSE>
__global__ __launch_bounds__(256, 2) void gemm_k(
    const void* __restrict__ Ain, const float* __restrict__ W,
    const float* __restrict__ bias, void* __restrict__ Cout,
    float* __restrict__ stats, const float* __restrict__ ss) {
  __shared__ float sA[128][65];
  __shared__ float sW[64][128];
  const int tid = threadIdx.x;
  const int tx = tid & 15, ty = tid >> 4;
  const int row0 = blockIdx.x * 128;
  float acc[8][8];
#pragma unroll
  for (int i = 0; i < 8; i++)
#pragma unroll
    for (int j = 0; j < 8; j++) acc[i][j] = 0.f;

  for (int kp = 0; kp < HD; kp += 64) {
    if (IN_BF16) {
      const u16* Ab = (const u16*)Ain;
#pragma unroll
      for (int it = 0; it < 4; it++) {
        int idx = tid + it * 256;     // 0..1023: 128 rows x 8 slots (8 bf16 each)
        int r = idx >> 3, c8 = idx & 7;
        int gr = row0 + r;
        float v[8] = {0.f, 0.f, 0.f, 0.f, 0.f, 0.f, 0.f, 0.f};
        if (gr < NN) {
          uint4 p = *(const uint4*)(Ab + (size_t)gr * HD + kp + c8 * 8);
          unp8(p, v);
        }
        if constexpr (FUSE) {
#pragma unroll
          for (int j = 0; j < 8; j++) {
            int cc = kp + c8 * 8 + j;
            v[j] = fmaxf(fmaf(v[j], ss[cc], ss[128 + cc]), 0.f);
          }
        }
#pragma unroll
        for (int j = 0; j < 8; j++) sA[r][c8 * 8 + j] = v[j];
      }
    } else {
      const float* Af = (const float*)Ain;
#pragma unroll
      for (int it = 0; it < 8; it++) {
        int idx = tid + it * 256;     // 0..2047: 128 rows x 16 float4 slots
        int r = idx >> 4, c4 = idx & 15;
        int gr = row0 + r;
        float4 v = make_float4(0.f, 0.f, 0.f, 0.f);
        if (gr < NN) v = *(const float4*)(Af + (size_t)gr * HD + kp + c4 * 4);
        sA[r][c4 * 4 + 0] = v.x; sA[r][c4 * 4 + 1] = v.y;
        sA[r][c4 * 4 + 2] = v.z; sA[r][c4 * 4 + 3] = v.w;
      }
    }
#pragma unroll
    for (int it = 0; it < 8; it++) {
      int idx = tid + it * 256;
      ((float4*)&sW[0][0])[idx] = ((const float4*)(W + (size_t)kp * HD))[idx];
    }
    __syncthreads();
#pragma unroll
    for (int k = 0; k < 64; k++) {
      float a[8];
#pragma unroll
      for (int i = 0; i < 8; i++) a[i] = sA[ty * 8 + i][k];
      float4 w0 = *(float4*)&sW[k][tx * 8];
      float4 w1 = *(float4*)&sW[k][tx * 8 + 4];
      float w[8] = {w0.x, w0.y, w0.z, w0.w, w1.x, w1.y, w1.z, w1.w};
#pragma unroll
      for (int i = 0; i < 8; i++)
#pragma unroll
        for (int j = 0; j < 8; j++) acc[i][j] = fmaf(a[i], w[j], acc[i][j]);
    }
    __syncthreads();
  }
  // epilogue: bias, store, BN stats
  float4 b0 = *(const float4*)(bias + tx * 8);
  float4 b1v = *(const float4*)(bias + tx * 8 + 4);
  float bb[8] = {b0.x, b0.y, b0.z, b0.w, b1v.x, b1v.y, b1v.z, b1v.w};
  float cs[8], cq[8];
#pragma unroll
  for (int j = 0; j < 8; j++) { cs[j] = 0.f; cq[j] = 0.f; }
#pragma unroll
  for (int i = 0; i < 8; i++) {
    int gr = row0 + ty * 8 + i;
    if (gr < NN) {
      float o[8];
#pragma unroll
      for (int j = 0; j < 8; j++) {
        o[j] = acc[i][j] + bb[j];
        cs[j] += o[j];
        cq[j] += o[j] * o[j];
      }
      if constexpr (OUT_BF16) {
        *(uint4*)((u16*)Cout + (size_t)gr * HD + tx * 8) = pk8(o);
      } else {
        *(float4*)((float*)Cout + (size_t)gr * HD + tx * 8) = make_float4(o[0], o[1], o[2], o[3]);
        *(float4*)((float*)Cout + (size_t)gr * HD + tx * 8 + 4) = make_float4(o[4], o[5], o[6], o[7]);
      }
    }
  }
  float* ps = &sW[0][0];
  float* pq = ps + 2048;
#pragma unroll
  for (int j = 0; j < 8; j++) {
    ps[ty * 128 + tx * 8 + j] = cs[j];
    pq[ty * 128 + tx * 8 + j] = cq[j];
  }
  __syncthreads();
  if (tid < HD) {
    float s = 0.f, q = 0.f;
#pragma unroll
    for (int g = 0; g < 16; g++) { s += ps[g * 128 + tid]; q += pq[g * 128 + tid]; }
    atomAddF(&stats[tid], s);
    atomAddF(&stats[HD + tid], q);
  }
}

// ---------------- stats -> scale/shift (writes base+256 / base+384) ----------------
__global__ __launch_bounds__(128) void scale_shift_k(float* __restrict__ stats,
    const float* __restrict__ g, const float* __restrict__ b) {
  int c = threadIdx.x;
  float mean = stats[c] * (1.0f / NN);
  float var = stats[HD + c] * (1.0f / NN) - mean * mean;
  float sc = g[c] * rsqrtf(var + BN_EPS);
  stats[256 + c] = sc;
  stats[384 + c] = fmaf(-mean, sc, b[c]);
}

// ---------------- BN apply on B -> A (bf16) (+relu), and zero B for next layer ----------------
__global__ __launch_bounds__(256) void bn_apply_zero_k(const float* __restrict__ Bin,
    float* __restrict__ Bz, u16* __restrict__ A, const float* __restrict__ ss, int relu) {
  int gid = blockIdx.x * 256 + threadIdx.x;
  if (gid >= NN * 16) return;
  int n = gid >> 4, c8 = gid & 15;
  const float* bp = Bin + (size_t)n * HD + c8 * 8;
  float4 b0 = *(const float4*)bp;
  float4 b1 = *(const float4*)(bp + 4);
  float v[8] = {b0.x, b0.y, b0.z, b0.w, b1.x, b1.y, b1.z, b1.w};
#pragma unroll
  for (int j = 0; j < 8; j++) {
    v[j] = fmaf(v[j], ss[c8 * 8 + j], ss[128 + c8 * 8 + j]);
    if (relu) v[j] = fmaxf(v[j], 0.f);
  }
  *(uint4*)(A + (size_t)n * HD + c8 * 8) = pk8(v);
  float* bz = Bz + (size_t)n * HD + c8 * 8;
  *(float4*)bz = make_float4(0.f, 0.f, 0.f, 0.f);
  *(float4*)(bz + 4) = make_float4(0.f, 0.f, 0.f, 0.f);
}

// ---------------- pool: pooled[batch[n]] += A[n] ----------------
__global__ __launch_bounds__(256) void pool_k(const u16* __restrict__ A,
    const int* __restrict__ batch, float* __restrict__ pooled) {
  int gid = blockIdx.x * 256 + threadIdx.x;
  if (gid >= NN * 16) return;
  int n = gid >> 4, c8 = gid & 15;
  int g = batch[n];
  uint4 p = *(const uint4*)(A + (size_t)n * HD + c8 * 8);
  float v[8]; unp8(p, v);
  float* dst = pooled + (size_t)g * HD + c8 * 8;
#pragma unroll
  for (int j = 0; j < 8; j++) atomAddF(dst + j, v[j]);
}

// ---------------- head: out[g] = relu(pooled@cw1+cb1)@cw2+cb2 ----------------
__global__ __launch_bounds__(128) void final_k(const float* __restrict__ pooled,
    const float* __restrict__ cw1, const float* __restrict__ cb1,
    const float* __restrict__ cw2, const float* __restrict__ cb2,
    float* __restrict__ out) {
  __shared__ float sp[128];
  __shared__ float sh[128];
  int g = blockIdx.x, t = threadIdx.x;
  sp[t] = pooled[(size_t)g * HD + t];
  __syncthreads();
  float acc = cb1[t];
#pragma unroll
  for (int k = 0; k < HD; k++) acc = fmaf(sp[k], cw1[k * HD + t], acc);
  acc = fmaxf(acc, 0.f);
  sh[t] = acc * cw2[t];
  __syncthreads();
  for (int s = 64; s >= 1; s >>= 1) {
    if (t < s) sh[t] += sh[t + s];
    __syncthreads();
  }
  if (t == 0) out[g] = sh[0] + cb2[0];
}

extern "C" void kernel_launch(void* const* d_in, const int* in_sizes, int n_in,
                              void* d_out, int out_size, void* d_ws, size_t ws_size,
                              hipStream_t stream) {
  const int*   x        = (const int*)d_in[0];
  const int*   ei       = (const int*)d_in[1];   // [2, E]
  const int*   ea       = (const int*)d_in[2];   // [E, 3]
  const int*   batch    = (const int*)d_in[3];
  const float* atom_emb = (const float*)d_in[4];
  const float* bond_emb = (const float*)d_in[5];
  const float* eps      = (const float*)d_in[6];
  const float* w1       = (const float*)d_in[7];
  const float* b1       = (const float*)d_in[8];
  const float* bn1_g    = (const float*)d_in[9];
  const float* bn1_b    = (const float*)d_in[10];
  const float* w2       = (const float*)d_in[11];
  const float* b2       = (const float*)d_in[12];
  const float* bn_g     = (const float*)d_in[13];
  const float* bn_b     = (const float*)d_in[14];
  const float* cw1      = (const float*)d_in[15];
  const float* cb1      = (const float*)d_in[16];
  const float* cw2      = (const float*)d_in[17];
  const float* cb2      = (const float*)d_in[18];
  float* out = (float*)d_out;

  const size_t NH = (size_t)NN * HD;
  float* ws     = (float*)d_ws;
  float* stats  = ws;                              // 5 * 1024 floats
  float* pooled = ws + 5 * 1024;                   // NG*HD floats
  float* inv    = pooled + (size_t)NG * HD;        // NN floats
  float* B      = inv + NN;                        // NH fp32 (16B-aligned offset)
  u16*   A      = (u16*)(B + NH);                  // NH bf16

  const int nb_n16 = (int)(((size_t)NN * 16 + 255) / 256);  // 18750
  const int nb_e16 = (int)(((size_t)NE * 16 + 255) / 256);  // 37500
  const int nb_e32 = (int)(((size_t)NE * 32 + 255) / 256);  // 75000
  const int nb_gemm = (NN + 127) / 128;                      // 2344

  // zero all accumulators (stats+pooled+inv contiguous) and B once
  hipMemsetAsync(ws, 0, (5 * 1024 + (size_t)NG * HD + NN) * sizeof(float), stream);
  hipMemsetAsync(B, 0, NH * sizeof(float), stream);

  deg_k<<<(NE + 255) / 256, 256, 0, stream>>>(ei, inv);
  inv_k<<<(NN + 255) / 256, 256, 0, stream>>>(inv);
  atom_encoder_k<<<nb_n16, 256, 0, stream>>>(x, atom_emb, A);

  for (int l = 0; l < NL; l++) {
    const float* be = bond_emb + (size_t)l * NBF * BVOC * HD;
    float* st = stats + (size_t)l * 1024;
    // bond scatter-sum into (zeroed) B
    bond_k<<<nb_e32, 256, 0, stream>>>(ei, ea, be, B);
    // A <- h_in (bf16); B <- (1+eps)*h_in
    hinz_k<<<nb_n16, 256, 0, stream>>>(A, B, inv, eps, l);
    // B[col] += h_in[row]  => B == z
    aggr_k<<<nb_e16, 256, 0, stream>>>(ei, A, B);
    // z @ w1 + b1 -> A (bf16), stats[0:256)
    gemm_k<false, true, false><<<nb_gemm, 256, 0, stream>>>(
        B, w1 + (size_t)l * HD * HD, b1 + (size_t)l * HD, A, st, nullptr);
    scale_shift_k<<<1, 128, 0, stream>>>(st, bn1_g + (size_t)l * HD, bn1_b + (size_t)l * HD);
    // relu(bn1(A)) @ w2 + b2 -> B (fp32), stats[512:768)
    gemm_k<true, false, true><<<nb_gemm, 256, 0, stream>>>(
        A, w2 + (size_t)l * HD * HD, b2 + (size_t)l * HD, B, st + 512, st + 256);
    scale_shift_k<<<1, 128, 0, stream>>>(st + 512, bn_g + (size_t)l * HD, bn_b + (size_t)l * HD);
    // A <- bn(B) (+relu except last); B <- 0 for next layer's bond scatter
    bn_apply_zero_k<<<nb_n16, 256, 0, stream>>>(B, B, A, st + 768, (l < NL - 1) ? 1 : 0);
  }

  pool_k<<<nb_n16, 256, 0, stream>>>(A, batch, pooled);
  final_k<<<NG, 128, 0, stream>>>(pooled, cw1, cb1, cw2, cb2, out);
}

// Round 3
// 2981.587 us; speedup vs baseline: 6.4621x; 6.4621x over previous
//
#include <hip/hip_runtime.h>
#include <cstdint>

#define NN 300000
#define NE 600000
#define HD 128
#define NL 5
#define NG 8192
#define AVOC 128
#define BVOC 8
#define NAF 9
#define NBF 3
#define BN_EPS 1e-5f

#define SCAN_B 2048
#define SCAN_NB ((NN + SCAN_B - 1) / SCAN_B)   // 147

typedef unsigned short u16;
typedef unsigned int u32;

static __device__ __forceinline__ void atomAddF(float* p, float v) { unsafeAtomicAdd(p, v); }

static __device__ __forceinline__ float bf2f(u16 v) {
  union { u32 u; float f; } c; c.u = ((u32)v) << 16; return c.f;
}
static __device__ __forceinline__ u16 f2bf(float f) {
  union { float f; u32 u; } c; c.f = f;
  u32 u = c.u;
  return (u16)((u + 0x7FFFu + ((u >> 16) & 1u)) >> 16);  // RNE
}
static __device__ __forceinline__ void unp8(uint4 p, float* v) {
  v[0] = bf2f((u16)(p.x & 0xffff)); v[1] = bf2f((u16)(p.x >> 16));
  v[2] = bf2f((u16)(p.y & 0xffff)); v[3] = bf2f((u16)(p.y >> 16));
  v[4] = bf2f((u16)(p.z & 0xffff)); v[5] = bf2f((u16)(p.z >> 16));
  v[6] = bf2f((u16)(p.w & 0xffff)); v[7] = bf2f((u16)(p.w >> 16));
}
static __device__ __forceinline__ uint4 pk8(const float* v) {
  uint4 p;
  p.x = ((u32)f2bf(v[1]) << 16) | f2bf(v[0]);
  p.y = ((u32)f2bf(v[3]) << 16) | f2bf(v[2]);
  p.z = ((u32)f2bf(v[5]) << 16) | f2bf(v[4]);
  p.w = ((u32)f2bf(v[7]) << 16) | f2bf(v[6]);
  return p;
}

// ================= CSR construction =================
__global__ __launch_bounds__(256) void count_k(const int* __restrict__ ei,
    int* __restrict__ cnt_row, int* __restrict__ cnt_col) {
  int e = blockIdx.x * 256 + threadIdx.x;
  if (e >= NE) return;
  atomicAdd(&cnt_row[ei[e]], 1);
  atomicAdd(&cnt_col[ei[NE + e]], 1);
}

// in-place exclusive scan, pass 1: intra-block (2048 elems) + block sums
__global__ __launch_bounds__(256) void scan_block_k(int* __restrict__ P, int* __restrict__ bsum) {
  __shared__ int s[256];
  int b = blockIdx.x, t = threadIdx.x;
  int base = b * SCAN_B + t * 8;
  int v[8]; int ts = 0;
#pragma unroll
  for (int j = 0; j < 8; j++) { v[j] = (base + j < NN) ? P[base + j] : 0; ts += v[j]; }
  s[t] = ts;
  __syncthreads();
  for (int off = 1; off < 256; off <<= 1) {
    int tmp = 0;
    if (t >= off) tmp = s[t - off];
    __syncthreads();
    if (t >= off) s[t] += tmp;
    __syncthreads();
  }
  if (t == 255) bsum[b] = s[255];
  int run = (t == 0) ? 0 : s[t - 1];
#pragma unroll
  for (int j = 0; j < 8; j++) {
    if (base + j < NN) P[base + j] = run;
    run += v[j];
  }
}

// pass 2: scan the block sums (SCAN_NB <= 256), write total to *totOut
__global__ __launch_bounds__(256) void scan_tops_k(int* __restrict__ bsum, int* __restrict__ totOut) {
  __shared__ int s[256];
  int t = threadIdx.x;
  s[t] = (t < SCAN_NB) ? bsum[t] : 0;
  __syncthreads();
  for (int off = 1; off < 256; off <<= 1) {
    int tmp = 0;
    if (t >= off) tmp = s[t - off];
    __syncthreads();
    if (t >= off) s[t] += tmp;
    __syncthreads();
  }
  if (t < SCAN_NB) bsum[t] = (t == 0) ? 0 : s[t - 1];
  if (t == 255) *totOut = s[255];
}

// pass 3: add block offsets
__global__ __launch_bounds__(256) void scan_add_k(int* __restrict__ P, const int* __restrict__ bsum) {
  int b = blockIdx.x, t = threadIdx.x;
  int off = bsum[b];
  int base = b * SCAN_B + t * 8;
#pragma unroll
  for (int j = 0; j < 8; j++)
    if (base + j < NN) P[base + j] += off;
}

__global__ __launch_bounds__(256) void fill_k(const int* __restrict__ ei,
    const int* __restrict__ ptr_row, const int* __restrict__ ptr_col,
    int* __restrict__ fillr, int* __restrict__ fillc,
    int* __restrict__ adj_row, int* __restrict__ adj_col) {
  int e = blockIdx.x * 256 + threadIdx.x;
  if (e >= NE) return;
  int r = ei[e], c = ei[NE + e];
  int p1 = atomicAdd(&fillr[r], 1);
  adj_row[ptr_row[r] + p1] = e;          // edge id for bond lookup
  int p2 = atomicAdd(&fillc[c], 1);
  adj_col[ptr_col[c] + p2] = r;          // source node for aggregation
}

__global__ __launch_bounds__(256) void inv_k(const int* __restrict__ ptr_row, float* __restrict__ inv) {
  int n = blockIdx.x * 256 + threadIdx.x;
  if (n < NN) inv[n] = 1.0f / ((float)(ptr_row[n + 1] - ptr_row[n]) + 1.0f);
}

// graph segment boundaries via binary search (batch is sorted)
__global__ __launch_bounds__(256) void gp_k(const int* __restrict__ batch, int* __restrict__ gp) {
  int g = blockIdx.x * 256 + threadIdx.x;
  if (g > NG) return;
  int lo = 0, hi = NN;
  while (lo < hi) { int mid = (lo + hi) >> 1; if (batch[mid] < g) lo = mid + 1; else hi = mid; }
  gp[g] = lo;
}

// ================= model kernels =================
__global__ __launch_bounds__(256) void atom_encoder_k(const int* __restrict__ x,
    const float* __restrict__ emb, u16* __restrict__ A) {
  int gid = blockIdx.x * 256 + threadIdx.x;
  if (gid >= NN * 16) return;
  int n = gid >> 4, c8 = gid & 15;
  float acc[8] = {0.f, 0.f, 0.f, 0.f, 0.f, 0.f, 0.f, 0.f};
#pragma unroll
  for (int f = 0; f < NAF; f++) {
    int v = x[n * NAF + f];
    const float* e = emb + ((size_t)(f * AVOC + v)) * HD + c8 * 8;
    float4 e0 = *(const float4*)e;
    float4 e1 = *(const float4*)(e + 4);
    acc[0] += e0.x; acc[1] += e0.y; acc[2] += e0.z; acc[3] += e0.w;
    acc[4] += e1.x; acc[5] += e1.y; acc[6] += e1.z; acc[7] += e1.w;
  }
  *(uint4*)(A + (size_t)n * HD + c8 * 8) = pk8(acc);
}

// per-node: h_in = h + inv * sum_{in-edges(row)} bond_emb(edge) ; A <- bf16(h_in)
__global__ __launch_bounds__(256) void bond_hin_k(const int* __restrict__ ea,
    const float* __restrict__ be, const int* __restrict__ ptr_row,
    const int* __restrict__ adj_row, const float* __restrict__ inv,
    u16* __restrict__ A) {
  int t = threadIdx.x;
  int n = blockIdx.x * 16 + (t >> 4);
  int c8 = t & 15;
  if (n >= NN) return;
  int beg = ptr_row[n], end = ptr_row[n + 1];
  float acc[8] = {0.f, 0.f, 0.f, 0.f, 0.f, 0.f, 0.f, 0.f};
  for (int i = beg; i < end; i++) {
    int e = adj_row[i];
    int a0 = ea[e * 3 + 0], a1 = ea[e * 3 + 1], a2 = ea[e * 3 + 2];
    const float* p0 = be + (size_t)a0 * HD + c8 * 8;
    const float* p1 = be + (size_t)(BVOC + a1) * HD + c8 * 8;
    const float* p2 = be + (size_t)(2 * BVOC + a2) * HD + c8 * 8;
    float4 x0 = *(const float4*)p0, x1 = *(const float4*)(p0 + 4);
    float4 y0 = *(const float4*)p1, y1 = *(const float4*)(p1 + 4);
    float4 z0 = *(const float4*)p2, z1 = *(const float4*)(p2 + 4);
    acc[0] += x0.x + y0.x + z0.x; acc[1] += x0.y + y0.y + z0.y;
    acc[2] += x0.z + y0.z + z0.z; acc[3] += x0.w + y0.w + z0.w;
    acc[4] += x1.x + y1.x + z1.x; acc[5] += x1.y + y1.y + z1.y;
    acc[6] += x1.z + y1.z + z1.z; acc[7] += x1.w + y1.w + z1.w;
  }
  float iv = inv[n];
  uint4 pa = *(const uint4*)(A + (size_t)n * HD + c8 * 8);
  float h[8]; unp8(pa, h);
#pragma unroll
  for (int j = 0; j < 8; j++) h[j] = fmaf(acc[j], iv, h[j]);
  *(uint4*)(A + (size_t)n * HD + c8 * 8) = pk8(h);
}

// per-node: z = (1+eps)*h_in[n] + sum_{in-edges(col)} h_in[src] -> B (fp32)
__global__ __launch_bounds__(256) void aggr_z_k(const int* __restrict__ ptr_col,
    const int* __restrict__ adj_col, const u16* __restrict__ A,
    float* __restrict__ B, const float* __restrict__ eps, int l) {
  int t = threadIdx.x;
  int n = blockIdx.x * 16 + (t >> 4);
  int c8 = t & 15;
  if (n >= NN) return;
  float s = 1.0f + eps[l];
  uint4 pa = *(const uint4*)(A + (size_t)n * HD + c8 * 8);
  float z[8]; unp8(pa, z);
#pragma unroll
  for (int j = 0; j < 8; j++) z[j] *= s;
  int beg = ptr_col[n], end = ptr_col[n + 1];
  for (int i = beg; i < end; i++) {
    int src = adj_col[i];
    uint4 ps = *(const uint4*)(A + (size_t)src * HD + c8 * 8);
    float v[8]; unp8(ps, v);
#pragma unroll
    for (int j = 0; j < 8; j++) z[j] += v[j];
  }
  float* bp = B + (size_t)n * HD + c8 * 8;
  *(float4*)bp = make_float4(z[0], z[1], z[2], z[3]);
  *(float4*)(bp + 4) = make_float4(z[4], z[5], z[6], z[7]);
}

// ---------------- GEMM: C[N,128] = f(A)[N,128] @ W[128,128] + bias, + BN stats ----------------
template<bool IN_BF16, bool OUT_BF16, bool FUSE>
__global__ __launch_bounds__(256, 2) void gemm_k(
    const void* __restrict__ Ain, const float* __restrict__ W,
    const float* __restrict__ bias, void* __restrict__ Cout,
    float* __restrict__ stats, const float* __restrict__ ss) {
  __shared__ float sA[128][65];
  __shared__ float sW[64][128];
  const int tid = threadIdx.x;
  const int tx = tid & 15, ty = tid >> 4;
  const int row0 = blockIdx.x * 128;
  float acc[8][8];
#pragma unroll
  for (int i = 0; i < 8; i++)
#pragma unroll
    for (int j = 0; j < 8; j++) acc[i][j] = 0.f;

  for (int kp = 0; kp < HD; kp += 64) {
    if (IN_BF16) {
      const u16* Ab = (const u16*)Ain;
#pragma unroll
      for (int it = 0; it < 4; it++) {
        int idx = tid + it * 256;
        int r = idx >> 3, c8 = idx & 7;
        int gr = row0 + r;
        float v[8] = {0.f, 0.f, 0.f, 0.f, 0.f, 0.f, 0.f, 0.f};
        if (gr < NN) {
          uint4 p = *(const uint4*)(Ab + (size_t)gr * HD + kp + c8 * 8);
          unp8(p, v);
        }
        if constexpr (FUSE) {
#pragma unroll
          for (int j = 0; j < 8; j++) {
            int cc = kp + c8 * 8 + j;
            v[j] = fmaxf(fmaf(v[j], ss[cc], ss[128 + cc]), 0.f);
          }
        }
#pragma unroll
        for (int j = 0; j < 8; j++) sA[r][c8 * 8 + j] = v[j];
      }
    } else {
      const float* Af = (const float*)Ain;
#pragma unroll
      for (int it = 0; it < 8; it++) {
        int idx = tid + it * 256;
        int r = idx >> 4, c4 = idx & 15;
        int gr = row0 + r;
        float4 v = make_float4(0.f, 0.f, 0.f, 0.f);
        if (gr < NN) v = *(const float4*)(Af + (size_t)gr * HD + kp + c4 * 4);
        sA[r][c4 * 4 + 0] = v.x; sA[r][c4 * 4 + 1] = v.y;
        sA[r][c4 * 4 + 2] = v.z; sA[r][c4 * 4 + 3] = v.w;
      }
    }
#pragma unroll
    for (int it = 0; it < 8; it++) {
      int idx = tid + it * 256;
      ((float4*)&sW[0][0])[idx] = ((const float4*)(W + (size_t)kp * HD))[idx];
    }
    __syncthreads();
#pragma unroll
    for (int k = 0; k < 64; k++) {
      float a[8];
#pragma unroll
      for (int i = 0; i < 8; i++) a[i] = sA[ty * 8 + i][k];
      float4 w0 = *(float4*)&sW[k][tx * 8];
      float4 w1 = *(float4*)&sW[k][tx * 8 + 4];
      float w[8] = {w0.x, w0.y, w0.z, w0.w, w1.x, w1.y, w1.z, w1.w};
#pragma unroll
      for (int i = 0; i < 8; i++)
#pragma unroll
        for (int j = 0; j < 8; j++) acc[i][j] = fmaf(a[i], w[j], acc[i][j]);
    }
    __syncthreads();
  }
  float4 b0 = *(const float4*)(bias + tx * 8);
  float4 b1v = *(const float4*)(bias + tx * 8 + 4);
  float bb[8] = {b0.x, b0.y, b0.z, b0.w, b1v.x, b1v.y, b1v.z, b1v.w};
  float cs[8], cq[8];
#pragma unroll
  for (int j = 0; j < 8; j++) { cs[j] = 0.f; cq[j] = 0.f; }
#pragma unroll
  for (int i = 0; i < 8; i++) {
    int gr = row0 + ty * 8 + i;
    if (gr < NN) {
      float o[8];
#pragma unroll
      for (int j = 0; j < 8; j++) {
        o[j] = acc[i][j] + bb[j];
        cs[j] += o[j];
        cq[j] += o[j] * o[j];
      }
      if constexpr (OUT_BF16) {
        *(uint4*)((u16*)Cout + (size_t)gr * HD + tx * 8) = pk8(o);
      } else {
        *(float4*)((float*)Cout + (size_t)gr * HD + tx * 8) = make_float4(o[0], o[1], o[2], o[3]);
        *(float4*)((float*)Cout + (size_t)gr * HD + tx * 8 + 4) = make_float4(o[4], o[5], o[6], o[7]);
      }
    }
  }
  float* ps = &sW[0][0];
  float* pq = ps + 2048;
#pragma unroll
  for (int j = 0; j < 8; j++) {
    ps[ty * 128 + tx * 8 + j] = cs[j];
    pq[ty * 128 + tx * 8 + j] = cq[j];
  }
  __syncthreads();
  if (tid < HD) {
    float s = 0.f, q = 0.f;
#pragma unroll
    for (int g = 0; g < 16; g++) { s += ps[g * 128 + tid]; q += pq[g * 128 + tid]; }
    atomAddF(&stats[tid], s);
    atomAddF(&stats[HD + tid], q);
  }
}

__global__ __launch_bounds__(128) void scale_shift_k(float* __restrict__ stats,
    const float* __restrict__ g, const float* __restrict__ b) {
  int c = threadIdx.x;
  float mean = stats[c] * (1.0f / NN);
  float var = stats[HD + c] * (1.0f / NN) - mean * mean;
  float sc = g[c] * rsqrtf(var + BN_EPS);
  stats[256 + c] = sc;
  stats[384 + c] = fmaf(-mean, sc, b[c]);
}

// BN apply on B -> A (bf16) (+relu)
__global__ __launch_bounds__(256) void bn_apply_k(const float* __restrict__ Bin,
    u16* __restrict__ A, const float* __restrict__ ss, int relu) {
  int gid = blockIdx.x * 256 + threadIdx.x;
  if (gid >= NN * 16) return;
  int n = gid >> 4, c8 = gid & 15;
  const float* bp = Bin + (size_t)n * HD + c8 * 8;
  float4 b0 = *(const float4*)bp;
  float4 b1 = *(const float4*)(bp + 4);
  float v[8] = {b0.x, b0.y, b0.z, b0.w, b1.x, b1.y, b1.z, b1.w};
#pragma unroll
  for (int j = 0; j < 8; j++) {
    v[j] = fmaf(v[j], ss[c8 * 8 + j], ss[128 + c8 * 8 + j]);
    if (relu) v[j] = fmaxf(v[j], 0.f);
  }
  *(uint4*)(A + (size_t)n * HD + c8 * 8) = pk8(v);
}

// fused global_add_pool + 2-layer MLP head; one block per graph
__global__ __launch_bounds__(128) void pool_final_k(const u16* __restrict__ A,
    const int* __restrict__ gp, const float* __restrict__ cw1,
    const float* __restrict__ cb1, const float* __restrict__ cw2,
    const float* __restrict__ cb2, float* __restrict__ out) {
  __shared__ float sp[128];
  __shared__ float sh[128];
  int g = blockIdx.x, t = threadIdx.x;
  int beg = gp[g], end = gp[g + 1];
  float acc = 0.f;
  for (int n = beg; n < end; n++) acc += bf2f(A[(size_t)n * HD + t]);
  sp[t] = acc;
  __syncthreads();
  float h1 = cb1[t];
#pragma unroll
  for (int k = 0; k < HD; k++) h1 = fmaf(sp[k], cw1[k * HD + t], h1);
  h1 = fmaxf(h1, 0.f);
  sh[t] = h1 * cw2[t];
  __syncthreads();
  for (int s = 64; s >= 1; s >>= 1) {
    if (t < s) sh[t] += sh[t + s];
    __syncthreads();
  }
  if (t == 0) out[g] = sh[0] + cb2[0];
}

extern "C" void kernel_launch(void* const* d_in, const int* in_sizes, int n_in,
                              void* d_out, int out_size, void* d_ws, size_t ws_size,
                              hipStream_t stream) {
  const int*   x        = (const int*)d_in[0];
  const int*   ei       = (const int*)d_in[1];
  const int*   ea       = (const int*)d_in[2];
  const int*   batch    = (const int*)d_in[3];
  const float* atom_emb = (const float*)d_in[4];
  const float* bond_emb = (const float*)d_in[5];
  const float* eps      = (const float*)d_in[6];
  const float* w1       = (const float*)d_in[7];
  const float* b1       = (const float*)d_in[8];
  const float* bn1_g    = (const float*)d_in[9];
  const float* bn1_b    = (const float*)d_in[10];
  const float* w2       = (const float*)d_in[11];
  const float* b2       = (const float*)d_in[12];
  const float* bn_g     = (const float*)d_in[13];
  const float* bn_b     = (const float*)d_in[14];
  const float* cw1      = (const float*)d_in[15];
  const float* cb1      = (const float*)d_in[16];
  const float* cw2      = (const float*)d_in[17];
  const float* cb2      = (const float*)d_in[18];
  float* out = (float*)d_out;

  const size_t NH = (size_t)NN * HD;
  float* ws = (float*)d_ws;
  float* stats   = ws;                               // 5*1024 floats
  int*   ptr_row = (int*)(ws + 5 * 1024);            // NN+1
  int*   ptr_col = ptr_row + (NN + 1);               // NN+1
  int*   adj_row = ptr_col + (NN + 1);               // NE
  int*   adj_col = adj_row + NE;                     // NE
  int*   gp      = adj_col + NE;                     // NG+1
  float* inv     = (float*)(gp + (NG + 1));          // NN
  size_t off = 5 * 1024 + 2 * (size_t)(NN + 1) + 2 * (size_t)NE + (NG + 1) + NN;
  off = (off + 3) & ~(size_t)3;                      // 16B align
  float* B = ws + off;                               // NH fp32
  u16*   A = (u16*)(B + NH);                         // NH bf16
  // setup-only temps aliased into B (B first written by aggr_z in layer 0)
  int* fillr = (int*)B;
  int* fillc = fillr + NN;
  int* bsums = fillc + NN;                           // SCAN_NB ints

  const int nb_n16 = (int)(((size_t)NN * 16 + 255) / 256);  // 18750
  const int nb_node = (NN + 15) / 16;                        // 18750
  const int nb_e  = (NE + 255) / 256;                        // 2344
  const int nb_gemm = (NN + 127) / 128;                      // 2344

  // ---- setup: CSR build + encoder + graph offsets ----
  hipMemsetAsync(stats, 0, 5 * 1024 * sizeof(float), stream);
  hipMemsetAsync(ptr_row, 0, 2 * (NN + 1) * sizeof(int), stream);
  hipMemsetAsync(fillr, 0, 2 * NN * sizeof(int), stream);

  count_k<<<nb_e, 256, 0, stream>>>(ei, ptr_row, ptr_col);
  scan_block_k<<<SCAN_NB, 256, 0, stream>>>(ptr_row, bsums);
  scan_tops_k<<<1, 256, 0, stream>>>(bsums, &ptr_row[NN]);
  scan_add_k<<<SCAN_NB, 256, 0, stream>>>(ptr_row, bsums);
  scan_block_k<<<SCAN_NB, 256, 0, stream>>>(ptr_col, bsums);
  scan_tops_k<<<1, 256, 0, stream>>>(bsums, &ptr_col[NN]);
  scan_add_k<<<SCAN_NB, 256, 0, stream>>>(ptr_col, bsums);
  inv_k<<<(NN + 255) / 256, 256, 0, stream>>>(ptr_row, inv);
  fill_k<<<nb_e, 256, 0, stream>>>(ei, ptr_row, ptr_col, fillr, fillc, adj_row, adj_col);
  atom_encoder_k<<<nb_n16, 256, 0, stream>>>(x, atom_emb, A);
  gp_k<<<(NG + 1 + 255) / 256, 256, 0, stream>>>(batch, gp);

  // ---- layers ----
  for (int l = 0; l < NL; l++) {
    const float* be = bond_emb + (size_t)l * NBF * BVOC * HD;
    float* st = stats + (size_t)l * 1024;
    bond_hin_k<<<nb_node, 256, 0, stream>>>(ea, be, ptr_row, adj_row, inv, A);
    aggr_z_k<<<nb_node, 256, 0, stream>>>(ptr_col, adj_col, A, B, eps, l);
    gemm_k<false, true, false><<<nb_gemm, 256, 0, stream>>>(
        B, w1 + (size_t)l * HD * HD, b1 + (size_t)l * HD, A, st, nullptr);
    scale_shift_k<<<1, 128, 0, stream>>>(st, bn1_g + (size_t)l * HD, bn1_b + (size_t)l * HD);
    gemm_k<true, false, true><<<nb_gemm, 256, 0, stream>>>(
        A, w2 + (size_t)l * HD * HD, b2 + (size_t)l * HD, B, st + 512, st + 256);
    scale_shift_k<<<1, 128, 0, stream>>>(st + 512, bn_g + (size_t)l * HD, bn_b + (size_t)l * HD);
    bn_apply_k<<<nb_n16, 256, 0, stream>>>(B, A, st + 768, (l < NL - 1) ? 1 : 0);
  }

  // ---- pooled head ----
  pool_final_k<<<NG, 128, 0, stream>>>(A, gp, cw1, cb1, cw2, cb2, out);
}